// Round 1
// baseline (268.838 us; speedup 1.0000x reference)
//
#include <hip/hip_runtime.h>
#include <hip/hip_bf16.h>

typedef __attribute__((ext_vector_type(8))) short bf16x8;
typedef __attribute__((ext_vector_type(4))) short s16x4;
typedef __attribute__((ext_vector_type(4))) float f32x4;

#define LDS_XS   264       // X chunk row stride (shorts): 256 + 8 pad (2-way banks = free)
#define LDS_QKS  136       // QK row stride: 128 + 8
#define LDS_VTS  72        // Vt row stride: 64 + 8
#define LDS_PTS  20        // P^T row stride: 16 + 4 (keeps 8B alignment of packed writes)
#define LDS_YS   72
#define OFF_QK   0
#define OFF_VT   8704      // 64*136
#define OFF_PT   13312     // +64*72
#define OFF_Y    18432     // +4*64*20
#define LDS_TOT  23040     // +64*72  (46080 B -> 3 blocks/CU)

__device__ __forceinline__ short f2b(float f) {
    union { float f; unsigned u; } v; v.f = f;
    unsigned r = v.u + 0x7FFFu + ((v.u >> 16) & 1u);   // round-to-nearest-even
    return (short)(r >> 16);
}

__global__ void cvt_weights(const float* __restrict__ W1, const float* __restrict__ W2,
                            short* __restrict__ w1b, short* __restrict__ w2b) {
    int i = blockIdx.x * 256 + threadIdx.x;
    if (i < 192 * 768) w1b[i] = f2b(W1[i]);
    if (i < 768 * 64)  w2b[i] = f2b(W2[i]);
}

template<bool WSB>
__device__ __forceinline__ bf16x8 loadW(const short* __restrict__ wb,
                                        const float* __restrict__ wf, int off) {
    if (WSB) {
        return *(const bf16x8*)(wb + off);
    } else {
        f32x4 a = *(const f32x4*)(wf + off);
        f32x4 b = *(const f32x4*)(wf + off + 4);
        bf16x8 r;
        r[0] = f2b(a[0]); r[1] = f2b(a[1]); r[2] = f2b(a[2]); r[3] = f2b(a[3]);
        r[4] = f2b(b[0]); r[5] = f2b(b[1]); r[6] = f2b(b[2]); r[7] = f2b(b[3]);
        return r;
    }
}

// One block per (b,s) window. 4 waves. Wave w owns:
//  - proj1: o-tiles {w, 4+w, 8+w} (16 cols each) x all 64 rows
//  - attn + proj2: q-rows [16w, 16w+16) x everything
template<bool WSB>
__global__ __launch_bounds__(256, 2)
void tiny_att(const float* __restrict__ x, const float* __restrict__ W1f,
              const float* __restrict__ b1v, const float* __restrict__ W2f,
              const float* __restrict__ b2v, const short* __restrict__ W1b,
              const short* __restrict__ W2b, float* __restrict__ out) {
    __shared__ __align__(16) short lds[LDS_TOT];
    const int tid  = threadIdx.x;
    const int wid  = tid >> 6;
    const int lane = tid & 63;
    const int g    = lane >> 4;   // 16-lane group (k-group of fragments)
    const int c    = lane & 15;   // position within group
    const int win  = blockIdx.x;
    const float* xg = x + (size_t)win * (64 * 768);
    const f32x4 zero4 = {0.f, 0.f, 0.f, 0.f};

    // ---------------- proj1: QKV[64][192] = X[64][768] @ W1^T ----------------
    f32x4 acc1[12];   // [row-tile 0..3][o-slot 0..2]
    #pragma unroll
    for (int i = 0; i < 12; ++i) acc1[i] = zero4;

    #pragma unroll 1
    for (int kc = 0; kc < 3; ++kc) {           // 3 k-chunks of 256
        if (kc) __syncthreads();
        #pragma unroll 8
        for (int i = 0; i < 16; ++i) {         // stage X chunk -> LDS bf16
            int idx = i * 256 + tid;
            int row = idx >> 6;
            int c4  = idx & 63;
            f32x4 v = *(const f32x4*)(xg + row * 768 + kc * 256 + c4 * 4);
            s16x4 sv;
            sv[0] = f2b(v[0]); sv[1] = f2b(v[1]); sv[2] = f2b(v[2]); sv[3] = f2b(v[3]);
            *(s16x4*)&lds[row * LDS_XS + c4 * 4] = sv;
        }
        __syncthreads();
        #pragma unroll 1
        for (int k8 = 0; k8 < 8; ++k8) {       // 8 K-steps of 32 per chunk
            int kk = k8 * 32 + 8 * g;
            bf16x8 a[4];
            #pragma unroll
            for (int rt = 0; rt < 4; ++rt)
                a[rt] = *(const bf16x8*)&lds[(16 * rt + c) * LDS_XS + kk];
            #pragma unroll
            for (int oi = 0; oi < 3; ++oi) {
                int ot = wid + 4 * oi;
                bf16x8 b = loadW<WSB>(W1b, W1f, (16 * ot + c) * 768 + kc * 256 + kk);
                #pragma unroll
                for (int rt = 0; rt < 4; ++rt)
                    acc1[rt * 3 + oi] = __builtin_amdgcn_mfma_f32_16x16x32_bf16(
                        a[rt], b, acc1[rt * 3 + oi], 0, 0, 0);
            }
        }
    }
    __syncthreads();   // X region dead; QKV regions alias it below

    // ---------------- bias + QKV -> LDS ----------------
    #pragma unroll
    for (int oi = 0; oi < 3; ++oi) {
        int ot = wid + 4 * oi;
        int o  = 16 * ot + c;
        float bias = b1v[o];
        #pragma unroll
        for (int rt = 0; rt < 4; ++rt) {
            f32x4 v = acc1[rt * 3 + oi];
            if (oi < 2) {        // Q (o<64) and K (64<=o<128) as [n][o] rows
                #pragma unroll
                for (int r = 0; r < 4; ++r)
                    lds[OFF_QK + (16 * rt + 4 * g + r) * LDS_QKS + o] = f2b(v[r] + bias);
            } else {             // V stored transposed: Vt[d][n]
                int d = o - 128;
                s16x4 sv;
                sv[0] = f2b(v[0] + bias); sv[1] = f2b(v[1] + bias);
                sv[2] = f2b(v[2] + bias); sv[3] = f2b(v[3] + bias);
                *(s16x4*)&lds[OFF_VT + d * LDS_VTS + 16 * rt + 4 * g] = sv;
            }
        }
    }
    __syncthreads();

    // ---------------- S = Q K^T (wave w: q-rows 16w..16w+15) ----------------
    f32x4 sc[4];
    #pragma unroll
    for (int mt = 0; mt < 4; ++mt) sc[mt] = zero4;
    #pragma unroll
    for (int ks = 0; ks < 2; ++ks) {
        bf16x8 aq = *(const bf16x8*)&lds[OFF_QK + (16 * wid + c) * LDS_QKS + 32 * ks + 8 * g];
        #pragma unroll
        for (int mt = 0; mt < 4; ++mt) {
            bf16x8 bk = *(const bf16x8*)&lds[OFF_QK + (16 * mt + c) * LDS_QKS + 64 + 32 * ks + 8 * g];
            sc[mt] = __builtin_amdgcn_mfma_f32_16x16x32_bf16(aq, bk, sc[mt], 0, 0, 0);
        }
    }

    // ---------------- softmax over m (in-lane over 4 m-tiles + 16-lane shfl reduce) --------
    float p[4][4];
    const float kS = 0.125f * 1.44269504088896f;   // 1/sqrt(64) * log2(e)
    #pragma unroll
    for (int r = 0; r < 4; ++r) {
        float m0 = fmaxf(fmaxf(sc[0][r], sc[1][r]), fmaxf(sc[2][r], sc[3][r]));
        m0 = fmaxf(m0, __shfl_xor(m0, 1));
        m0 = fmaxf(m0, __shfl_xor(m0, 2));
        m0 = fmaxf(m0, __shfl_xor(m0, 4));
        m0 = fmaxf(m0, __shfl_xor(m0, 8));
        float s0 = 0.f;
        float pr[4];
        #pragma unroll
        for (int mt = 0; mt < 4; ++mt) {
            pr[mt] = exp2f((sc[mt][r] - m0) * kS);
            s0 += pr[mt];
        }
        s0 += __shfl_xor(s0, 1);
        s0 += __shfl_xor(s0, 2);
        s0 += __shfl_xor(s0, 4);
        s0 += __shfl_xor(s0, 8);
        float inv = __builtin_amdgcn_rcpf(s0);
        #pragma unroll
        for (int mt = 0; mt < 4; ++mt) p[mt][r] = pr[mt] * inv;
    }

    // ---------------- P^T -> LDS (per-wave region, packed b64 writes) ----------------
    const int ptb = OFF_PT + wid * (64 * LDS_PTS);
    #pragma unroll
    for (int mt = 0; mt < 4; ++mt) {
        s16x4 sv;
        sv[0] = f2b(p[mt][0]); sv[1] = f2b(p[mt][1]);
        sv[2] = f2b(p[mt][2]); sv[3] = f2b(p[mt][3]);
        *(s16x4*)&lds[ptb + (16 * mt + c) * LDS_PTS + 4 * g] = sv;
    }

    // ---------------- Y^T = V^T @ P^T  (D[d][n]) ----------------
    f32x4 y4[4];
    #pragma unroll
    for (int it = 0; it < 4; ++it) y4[it] = zero4;
    #pragma unroll
    for (int ks = 0; ks < 2; ++ks) {
        bf16x8 pb;
        #pragma unroll
        for (int j = 0; j < 8; ++j)
            pb[j] = lds[ptb + (32 * ks + 8 * g + j) * LDS_PTS + c];
        #pragma unroll
        for (int it = 0; it < 4; ++it) {
            bf16x8 av = *(const bf16x8*)&lds[OFF_VT + (16 * it + c) * LDS_VTS + 32 * ks + 8 * g];
            y4[it] = __builtin_amdgcn_mfma_f32_16x16x32_bf16(av, pb, y4[it], 0, 0, 0);
        }
    }
    // Y[n][d] -> LDS (packed along d)
    #pragma unroll
    for (int it = 0; it < 4; ++it) {
        s16x4 sv;
        sv[0] = f2b(y4[it][0]); sv[1] = f2b(y4[it][1]);
        sv[2] = f2b(y4[it][2]); sv[3] = f2b(y4[it][3]);
        *(s16x4*)&lds[OFF_Y + (16 * wid + c) * LDS_YS + 16 * it + 4 * g] = sv;
    }

    // ---------------- proj2: out[16 rows][768] = Y @ W2^T + b2 ----------------
    bf16x8 ay0 = *(const bf16x8*)&lds[OFF_Y + (16 * wid + c) * LDS_YS + 8 * g];
    bf16x8 ay1 = *(const bf16x8*)&lds[OFF_Y + (16 * wid + c) * LDS_YS + 32 + 8 * g];
    float* orow = out + ((size_t)win * 64 + 16 * wid) * 768;
    #pragma unroll 1
    for (int ch = 0; ch < 4; ++ch) {           // 4 chunks of 12 o-tiles (48 acc VGPRs each)
        f32x4 a2[12];
        #pragma unroll
        for (int i = 0; i < 12; ++i) a2[i] = zero4;
        #pragma unroll
        for (int oi = 0; oi < 12; ++oi) {
            int off = (16 * (ch * 12 + oi) + c) * 64;
            bf16x8 bw0 = loadW<WSB>(W2b, W2f, off + 8 * g);
            a2[oi] = __builtin_amdgcn_mfma_f32_16x16x32_bf16(ay0, bw0, a2[oi], 0, 0, 0);
            bf16x8 bw1 = loadW<WSB>(W2b, W2f, off + 32 + 8 * g);
            a2[oi] = __builtin_amdgcn_mfma_f32_16x16x32_bf16(ay1, bw1, a2[oi], 0, 0, 0);
        }
        #pragma unroll
        for (int oi = 0; oi < 12; ++oi) {
            int o = 16 * (ch * 12 + oi) + c;
            float bias = b2v[o];
            #pragma unroll
            for (int r = 0; r < 4; ++r)
                orow[(size_t)(4 * g + r) * 768 + o] = a2[oi][r] + bias;
        }
    }
}

extern "C" void kernel_launch(void* const* d_in, const int* in_sizes, int n_in,
                              void* d_out, int out_size, void* d_ws, size_t ws_size,
                              hipStream_t stream) {
    const float* x  = (const float*)d_in[0];
    const float* W1 = (const float*)d_in[1];
    const float* b1 = (const float*)d_in[2];
    const float* W2 = (const float*)d_in[3];
    const float* b2 = (const float*)d_in[4];
    float* out = (float*)d_out;
    const int nwin = in_sizes[0] / (64 * 768);   // 2048 windows
    const size_t need = (size_t)(192 * 768 + 768 * 64) * sizeof(short);
    if (ws_size >= need) {
        short* w1b = (short*)d_ws;
        short* w2b = w1b + 192 * 768;
        cvt_weights<<<576, 256, 0, stream>>>(W1, W2, w1b, w2b);
        tiny_att<true><<<nwin, 256, 0, stream>>>(x, W1, b1, W2, b2, w1b, w2b, out);
    } else {
        tiny_att<false><<<nwin, 256, 0, stream>>>(x, W1, b1, W2, b2, nullptr, nullptr, out);
    }
}